// Round 6
// baseline (63.580 us; speedup 1.0000x reference)
//
#include <hip/hip_runtime.h>
#include <stdint.h>

// IDs in [0, 100000): 100000 bits -> 3125 u32 words; pad to 3136 (x64) so
// every bitset slice is 16B-aligned for uint4 ops.
#define NWORDS 3125
#define NWP    3136
#define NVEC   (NWP / 4)              // 784 uint4 per bitset
#define SCAN_BLOCKS 1024
#define SCAN_THREADS 512
#define NCHUNK 32                     // stage-A partial bitsets
#define CHUNK  (SCAN_BLOCKS / NCHUNK) // 32 copies OR'd per stage-A thread

// int4 with alignment relaxed to 4B: gfx950 supports dword-aligned dwordx4.
typedef int4 __attribute__((aligned(4))) int4_a4;

__global__ void zero_kernel(uint32_t* __restrict__ w, int n) {
    int i = blockIdx.x * blockDim.x + threadIdx.x;
    if (i < n) w[i] = 0u;
}

__global__ void build_hr_kernel(const int* __restrict__ neg, int B,
                                uint32_t* __restrict__ headb,
                                uint32_t* __restrict__ relb) {
    int b = blockIdx.x * blockDim.x + threadIdx.x;
    if (b < B - 1) {
        int4 v = *(const int4_a4*)((const char*)neg + (uint32_t)b * 12u);
        atomicOr(&headb[v.x >> 5], 1u << (v.x & 31));
        atomicOr(&relb[v.y >> 5], 1u << (v.y & 31));
    } else if (b == B - 1) {  // last triple scalar: no over-read
        int h = neg[b * 3 + 0];
        int r = neg[b * 3 + 1];
        atomicOr(&headb[h >> 5], 1u << (h & 31));
        atomicOr(&relb[r >> 5], 1u << (r & 31));
    }
}

// Stream mapped_triples (overlapping 16B loads at 12B stride; h,r,t in
// .x,.y,.z). SHORT-CIRCUIT gathers: r-bit only if h-bit passes (~48%),
// tail update is one fire-and-forget LDS atomicOr (~23%).
// Active-lane LDS bank-ops/triple: 1 + 0.48 + 0.23 = 1.71 (was 2.5).
__global__ __launch_bounds__(SCAN_THREADS, 8) void scan_triples_kernel(
        const int* __restrict__ mt, int N,
        const uint32_t* __restrict__ headb,
        const uint32_t* __restrict__ relb,
        uint32_t* __restrict__ copies) {
    __shared__ __align__(16) uint32_t sh[NWP];
    __shared__ __align__(16) uint32_t sr[NWP];
    __shared__ __align__(16) uint32_t st[NWP];

    uint4* sh4 = (uint4*)sh;
    uint4* sr4 = (uint4*)sr;
    uint4* st4 = (uint4*)st;
    const uint4* hb4 = (const uint4*)headb;
    const uint4* rb4 = (const uint4*)relb;
    for (int i = threadIdx.x; i < NVEC; i += blockDim.x) {
        sh4[i] = hb4[i];
        sr4[i] = rb4[i];
        st4[i] = make_uint4(0u, 0u, 0u, 0u);
    }
    __syncthreads();

    const uint32_t tid = blockIdx.x * blockDim.x + threadIdx.x;
    const uint32_t stride = gridDim.x * blockDim.x;
    const char* __restrict__ base = (const char*)mt;

    for (uint32_t i = tid; i < (uint32_t)(N - 1); i += stride) {
        int4 v = *(const int4_a4*)(base + i * 12u);
        int h = v.x, r = v.y, t = v.z;
        if ((sh[h >> 5] >> (h & 31)) & 1u) {
            if ((sr[r >> 5] >> (r & 31)) & 1u) {
                atomicOr(&st[t >> 5], 1u << (t & 31));
            }
        }
    }
    if (tid == 0) {  // last triple, scalar (no over-read)
        int h = mt[(size_t)(N - 1) * 3 + 0];
        int r = mt[(size_t)(N - 1) * 3 + 1];
        int t = mt[(size_t)(N - 1) * 3 + 2];
        if (((sh[h >> 5] >> (h & 31)) & 1u) && ((sr[r >> 5] >> (r & 31)) & 1u))
            atomicOr(&st[t >> 5], 1u << (t & 31));
    }

    __syncthreads();
    uint4* dst4 = (uint4*)(copies + (size_t)blockIdx.x * NWP);
    for (int i = threadIdx.x; i < NVEC; i += blockDim.x) dst4[i] = st4[i];
}

// Stage A: OR-reduce SCAN_BLOCKS copies into NCHUNK partials (plain stores).
__global__ void reduceA_kernel(const uint32_t* __restrict__ copies,
                               uint32_t* __restrict__ partials) {
    int idx = blockIdx.x * blockDim.x + threadIdx.x;
    if (idx >= NCHUNK * NVEC) return;
    int i  = idx % NVEC;
    int ch = idx / NVEC;
    const uint4* c4 = (const uint4*)copies;
    uint4 acc = make_uint4(0u, 0u, 0u, 0u);
    int c0 = ch * CHUNK;
    for (int c = 0; c < CHUNK; ++c) {
        uint4 v = c4[(size_t)(c0 + c) * NVEC + i];
        acc.x |= v.x; acc.y |= v.y; acc.z |= v.z; acc.w |= v.w;
    }
    ((uint4*)partials)[(size_t)ch * NVEC + i] = acc;
}

// Stage B: OR the NCHUNK partials into one final tail bitset.
__global__ void reduceB_kernel(const uint32_t* __restrict__ partials,
                               uint32_t* __restrict__ final_b) {
    int w = blockIdx.x * blockDim.x + threadIdx.x;
    if (w >= NWP) return;
    uint32_t acc = 0u;
#pragma unroll
    for (int c = 0; c < NCHUNK; ++c) acc |= partials[c * NWP + w];
    final_b[w] = acc;
}

__global__ void finalize_kernel(const int* __restrict__ neg, int B,
                                const uint32_t* __restrict__ final_b,
                                int* __restrict__ out) {
    int b = blockIdx.x * blockDim.x + threadIdx.x;
    if (b >= B) return;
    int h = neg[b * 3 + 0];
    int r = neg[b * 3 + 1];
    int t = neg[b * 3 + 2];
    bool filtered = (final_b[t >> 5] >> (t & 31)) & 1u;
    int keep = filtered ? 0 : 1;
    out[b * 3 + 0] = keep ? h : -1;
    out[b * 3 + 1] = keep ? r : -1;
    out[b * 3 + 2] = keep ? t : -1;
    out[3 * B + b] = keep;  // keep_mask as 0/1 int32
}

extern "C" void kernel_launch(void* const* d_in, const int* in_sizes, int n_in,
                              void* d_out, int out_size, void* d_ws, size_t ws_size,
                              hipStream_t stream) {
    const int* neg = (const int*)d_in[0];   // [B,3] int32
    const int* mt  = (const int*)d_in[1];   // [N,3] int32
    int B = in_sizes[0] / 3;
    int N = in_sizes[1] / 3;
    int* out = (int*)d_out;

    uint32_t* ws       = (uint32_t*)d_ws;
    uint32_t* headb    = ws;                       // NWP
    uint32_t* relb     = ws + NWP;                 // NWP
    uint32_t* final_b  = ws + 2 * NWP;             // NWP
    uint32_t* partials = ws + 3 * NWP;             // NCHUNK * NWP
    uint32_t* copies   = ws + (3 + NCHUNK) * NWP;  // SCAN_BLOCKS * NWP (~12.8 MB)

    // zero head/rel bitsets (ws not re-poisoned between replays; copies/
    // partials/final fully overwritten every call before being read)
    zero_kernel<<<(2 * NWP + 255) / 256, 256, 0, stream>>>(ws, 2 * NWP);
    build_hr_kernel<<<(B + 255) / 256, 256, 0, stream>>>(neg, B, headb, relb);
    scan_triples_kernel<<<SCAN_BLOCKS, SCAN_THREADS, 0, stream>>>(
        mt, N, headb, relb, copies);
    {
        int total = NCHUNK * NVEC;
        reduceA_kernel<<<(total + 255) / 256, 256, 0, stream>>>(copies, partials);
    }
    reduceB_kernel<<<(NWP + 255) / 256, 256, 0, stream>>>(partials, final_b);
    finalize_kernel<<<(B + 255) / 256, 256, 0, stream>>>(neg, B, final_b, out);
}

// Round 7
// 55.829 us; speedup vs baseline: 1.1388x; 1.1388x over previous
//
#include <hip/hip_runtime.h>
#include <stdint.h>

// IDs in [0, 100000): 100000 bits -> 3125 u32 words; pad to 3136 (x64) so
// every bitset slice is 16B-aligned for uint4 ops.
#define NWORDS 3125
#define NWP    3136
#define NVEC   (NWP / 4)              // 784 uint4 per bitset
#define SCAN_BLOCKS 1024
#define SCAN_THREADS 512
#define NPART  8                      // partial tail bitsets (collision spread)

// int4 with alignment relaxed to 4B: gfx950 supports dword-aligned dwordx4.
typedef int4 __attribute__((aligned(4))) int4_a4;

__global__ void zero_kernel(uint32_t* __restrict__ w, int n) {
    int i = blockIdx.x * blockDim.x + threadIdx.x;
    if (i < n) w[i] = 0u;
}

__global__ void build_hr_kernel(const int* __restrict__ neg, int B,
                                uint32_t* __restrict__ headb,
                                uint32_t* __restrict__ relb) {
    int b = blockIdx.x * blockDim.x + threadIdx.x;
    if (b >= B) return;
    int h = neg[b * 3 + 0];
    int r = neg[b * 3 + 1];
    atomicOr(&headb[h >> 5], 1u << (h & 31));
    atomicOr(&relb[r >> 5], 1u << (r & 31));
}

// Stream mapped_triples (overlapping 16B loads at 12B stride; h,r,t arrive in
// .x,.y,.z — no repack). Branchless h&r test (R4 form). Surviving tails are
// marked in a per-block LDS bitset, then flushed with global atomicOr into
// one of NPART partial bitsets (blockIdx&7) — ~88-way per-address collisions,
// L2-resident, no copies round-trip.
__global__ __launch_bounds__(SCAN_THREADS, 8) void scan_triples_kernel(
        const int* __restrict__ mt, int N,
        const uint32_t* __restrict__ headb,
        const uint32_t* __restrict__ relb,
        uint32_t* __restrict__ parts) {
    __shared__ __align__(16) uint32_t sh[NWP];
    __shared__ __align__(16) uint32_t sr[NWP];
    __shared__ __align__(16) uint32_t st[NWP];

    uint4* sh4 = (uint4*)sh;
    uint4* sr4 = (uint4*)sr;
    uint4* st4 = (uint4*)st;
    const uint4* hb4 = (const uint4*)headb;
    const uint4* rb4 = (const uint4*)relb;
    for (int i = threadIdx.x; i < NVEC; i += blockDim.x) {
        sh4[i] = hb4[i];
        sr4[i] = rb4[i];
        st4[i] = make_uint4(0u, 0u, 0u, 0u);
    }
    __syncthreads();

    const uint32_t tid = blockIdx.x * blockDim.x + threadIdx.x;
    const uint32_t stride = gridDim.x * blockDim.x;
    const char* __restrict__ base = (const char*)mt;

    // all but last triple: in-bounds 4B over-read because triple i+1 exists
    for (uint32_t i = tid; i < (uint32_t)(N - 1); i += stride) {
        int4 v = *(const int4_a4*)(base + i * 12u);
        int h = v.x, r = v.y, t = v.z;
        uint32_t hbit = (sh[h >> 5] >> (h & 31)) & 1u;
        uint32_t rbit = (sr[r >> 5] >> (r & 31)) & 1u;
        if (hbit & rbit) {
            uint32_t bit = 1u << (t & 31);
            if (!(st[t >> 5] & bit)) atomicOr(&st[t >> 5], bit);
        }
    }
    if (tid == 0) {  // last triple, scalar (no over-read)
        int h = mt[(size_t)(N - 1) * 3 + 0];
        int r = mt[(size_t)(N - 1) * 3 + 1];
        int t = mt[(size_t)(N - 1) * 3 + 2];
        if (((sh[h >> 5] >> (h & 31)) & 1u) && ((sr[r >> 5] >> (r & 31)) & 1u))
            atomicOr(&st[t >> 5], 1u << (t & 31));
    }

    __syncthreads();
    // flush nonzero words straight into one of NPART global partial bitsets
    uint32_t* dst = parts + (size_t)(blockIdx.x & (NPART - 1)) * NWP;
    for (int i = threadIdx.x; i < NWORDS; i += blockDim.x) {
        uint32_t v = st[i];
        if (v) atomicOr(&dst[i], v);
    }
}

__global__ void finalize_kernel(const int* __restrict__ neg, int B,
                                const uint32_t* __restrict__ parts,
                                int* __restrict__ out) {
    int b = blockIdx.x * blockDim.x + threadIdx.x;
    if (b >= B) return;
    int h = neg[b * 3 + 0];
    int r = neg[b * 3 + 1];
    int t = neg[b * 3 + 2];
    int w = t >> 5;
    uint32_t acc = 0u;
#pragma unroll
    for (int c = 0; c < NPART; ++c) acc |= parts[c * NWP + w];
    bool filtered = (acc >> (t & 31)) & 1u;
    int keep = filtered ? 0 : 1;
    out[b * 3 + 0] = keep ? h : -1;
    out[b * 3 + 1] = keep ? r : -1;
    out[b * 3 + 2] = keep ? t : -1;
    out[3 * B + b] = keep;  // keep_mask as 0/1 int32
}

extern "C" void kernel_launch(void* const* d_in, const int* in_sizes, int n_in,
                              void* d_out, int out_size, void* d_ws, size_t ws_size,
                              hipStream_t stream) {
    const int* neg = (const int*)d_in[0];   // [B,3] int32
    const int* mt  = (const int*)d_in[1];   // [N,3] int32
    int B = in_sizes[0] / 3;
    int N = in_sizes[1] / 3;
    int* out = (int*)d_out;

    uint32_t* ws    = (uint32_t*)d_ws;
    uint32_t* headb = ws;               // NWP
    uint32_t* relb  = ws + NWP;         // NWP
    uint32_t* parts = ws + 2 * NWP;     // NPART * NWP (~100 KB, L2-resident)

    // zero head/rel bitsets + partial tail bitsets (ws not re-poisoned
    // between replays — must re-zero every call)
    zero_kernel<<<((2 + NPART) * NWP + 255) / 256, 256, 0, stream>>>(
        ws, (2 + NPART) * NWP);
    build_hr_kernel<<<(B + 255) / 256, 256, 0, stream>>>(neg, B, headb, relb);
    scan_triples_kernel<<<SCAN_BLOCKS, SCAN_THREADS, 0, stream>>>(
        mt, N, headb, relb, parts);
    finalize_kernel<<<(B + 255) / 256, 256, 0, stream>>>(neg, B, parts, out);
}